// Round 1
// baseline (310.960 us; speedup 1.0000x reference)
//
#include <hip/hip_runtime.h>

// CenterLoss: B=32, T=256, D=96, C=6625, N=B*T=8192.
// loss = mean_n clip(||f_n - centers[argmax_c predicts[n,c]]||^2, EPS, INF)
//        + (C-1)*EPS      // masked-out zeros each clip up to EPS
//
// Memory-bound on the predicts scan: 8192*6625*4B ~= 217 MB.

#define EPS_F 1e-7f
#define INF_F 1e11f

constexpr int C_DIM = 6625;
constexpr int D_DIM = 96;

__global__ __launch_bounds__(256) void center_loss_main(
    const float* __restrict__ feats,      // [N, 96]
    const float* __restrict__ predicts,   // [N, 6625]
    const float* __restrict__ centers,    // [6625, 96]
    float* __restrict__ ws_part)          // [N] clipped distances
{
    const int n = blockIdx.x;
    const int t = threadIdx.x;
    const float* __restrict__ row = predicts + (size_t)n * C_DIM;

    float best = -3.4e38f;
    int   bidx = 0;

    // Row base is only 4B-aligned (6625 floats stride). Peel to 16B.
    const int mis    = (int)(((size_t)n * (size_t)C_DIM) & 3);  // elements past 16B
    const int prefix = (4 - mis) & 3;
    if (t < prefix) {
        float v = row[t];
        if (v > best) { best = v; bidx = t; }
    }
    const int nvec = (C_DIM - prefix) >> 2;
    const float4* __restrict__ vrow = (const float4*)(row + prefix);
    for (int k = t; k < nvec; k += 256) {
        float4 v = vrow[k];
        int c0 = prefix + 4 * k;
        if (v.x > best) { best = v.x; bidx = c0;     }
        if (v.y > best) { best = v.y; bidx = c0 + 1; }
        if (v.z > best) { best = v.z; bidx = c0 + 2; }
        if (v.w > best) { best = v.w; bidx = c0 + 3; }
    }
    const int tail_start = prefix + 4 * nvec;
    if (t < C_DIM - tail_start) {
        int c = tail_start + t;
        float v = row[c];
        if (v > best) { best = v; bidx = c; }
    }

    // Wave (64-lane) argmax reduce, tie -> smaller index.
    #pragma unroll
    for (int off = 32; off > 0; off >>= 1) {
        float ov = __shfl_down(best, off);
        int   oi = __shfl_down(bidx, off);
        if (ov > best || (ov == best && oi < bidx)) { best = ov; bidx = oi; }
    }

    __shared__ float s_val[4];
    __shared__ int   s_idx[4];
    __shared__ int   s_label;
    if ((t & 63) == 0) { s_val[t >> 6] = best; s_idx[t >> 6] = bidx; }
    __syncthreads();
    if (t == 0) {
        float bv = s_val[0]; int bi = s_idx[0];
        #pragma unroll
        for (int w = 1; w < 4; ++w) {
            if (s_val[w] > bv || (s_val[w] == bv && s_idx[w] < bi)) {
                bv = s_val[w]; bi = s_idx[w];
            }
        }
        s_label = bi;
    }
    __syncthreads();

    // Distance for this row: wave 0 only (all 64 lanes active -> safe shfl).
    if (t < 64) {
        const int label = s_label;
        const float* __restrict__ f = feats   + (size_t)n     * D_DIM;
        const float* __restrict__ c = centers + (size_t)label * D_DIM;
        float diff = f[t] - c[t];
        float s = diff * diff;
        if (t < 32) {
            float d2 = f[t + 64] - c[t + 64];
            s += d2 * d2;
        }
        #pragma unroll
        for (int off = 32; off > 0; off >>= 1) s += __shfl_down(s, off);
        if (t == 0) ws_part[n] = fminf(fmaxf(s, EPS_F), INF_F);
    }
}

__global__ __launch_bounds__(256) void center_loss_final(
    const float* __restrict__ ws_part, float* __restrict__ out, int N)
{
    const int t = threadIdx.x;
    float s = 0.f;
    for (int i = t; i < N; i += 256) s += ws_part[i];
    #pragma unroll
    for (int off = 32; off > 0; off >>= 1) s += __shfl_down(s, off);
    __shared__ float s_s[4];
    if ((t & 63) == 0) s_s[t >> 6] = s;
    __syncthreads();
    if (t == 0) {
        float tot = s_s[0] + s_s[1] + s_s[2] + s_s[3];
        out[0] = tot / (float)N + (float)(C_DIM - 1) * EPS_F;
    }
}

extern "C" void kernel_launch(void* const* d_in, const int* in_sizes, int n_in,
                              void* d_out, int out_size, void* d_ws, size_t ws_size,
                              hipStream_t stream) {
    const float* feats    = (const float*)d_in[0];  // [32,256,96]
    const float* predicts = (const float*)d_in[1];  // [32,256,6625]
    const float* centers  = (const float*)d_in[2];  // [6625,96]
    float* out = (float*)d_out;

    const int N = in_sizes[0] / D_DIM;  // 8192
    float* ws_part = (float*)d_ws;      // N floats

    center_loss_main<<<N, 256, 0, stream>>>(feats, predicts, centers, ws_part);
    center_loss_final<<<1, 256, 0, stream>>>(ws_part, out, N);
}